// Round 1
// baseline (1417.585 us; speedup 1.0000x reference)
//
#include <hip/hip_runtime.h>

// SAGEConv: agg = segment_sum(x[src]*w, dst); out = agg@W_l + b_l + x@W_r + b_r;
// out /= max(sum|out|, 1e-12) row-wise.
// N=100000, E=1600000, D=128.

static constexpr int D = 128;

// ---------------- scatter: agg[dst] += x[src] * w ----------------
// one wave per edge; lane handles float2 of the 128-wide feature row.
__global__ __launch_bounds__(256) void sage_scatter(
    const float* __restrict__ x,
    const int* __restrict__ esrc,
    const int* __restrict__ edst,
    const float* __restrict__ ew,
    float* agg,          // = d_out (in-place scratch), pre-zeroed
    int E)
{
    const int lane = threadIdx.x & 63;
    const int warp = (blockIdx.x * blockDim.x + threadIdx.x) >> 6;
    const int nwarps = (gridDim.x * blockDim.x) >> 6;
    const float2* __restrict__ x2 = reinterpret_cast<const float2*>(x);
    for (int e = warp; e < E; e += nwarps) {
        const int s = esrc[e];
        const int d = edst[e];
        const float w = ew[e];
        const float2 xv = x2[s * 64 + lane];
        atomicAdd(&agg[d * D + lane * 2 + 0], xv.x * w);
        atomicAdd(&agg[d * D + lane * 2 + 1], xv.y * w);
    }
}

// ------------- fused linear(l)+linear(r)+bias+L1-normalize -------------
// block: 256 threads, 64 nodes. jg = tid&31 owns 4 output features,
// ng = tid>>5 owns 8 nodes. acc[8][4] register tile.
// K loop: 4 chunks of 64 (agg k0-63, agg k64-127, x k0-63, x k64-127).
__global__ __launch_bounds__(256) void sage_linear_norm(
    const float* agg,    // aliases out (d_out) — reads complete before writes
    const float* __restrict__ x,
    const float* __restrict__ Wl,
    const float* __restrict__ bl,
    const float* __restrict__ Wr,
    const float* __restrict__ br,
    float* out,
    int N)
{
    __shared__ float a_s[64][68];   // pad 4: keeps rows 16B-aligned for b128
    const int tid = threadIdx.x;
    const int jg = tid & 31;        // feature group (4 features)
    const int ng = tid >> 5;        // node group (8 nodes)
    const int bn = blockIdx.x * 64;

    float acc[8][4];
#pragma unroll
    for (int i = 0; i < 8; ++i) {
        acc[i][0] = 0.f; acc[i][1] = 0.f; acc[i][2] = 0.f; acc[i][3] = 0.f;
    }

    const int sn  = tid >> 2;        // staging: node within tile
    const int skb = (tid & 3) << 4;  // staging: k offset base

    for (int c = 0; c < 4; ++c) {
        const float* A = (c < 2) ? agg : x;
        const float* __restrict__ W = (c < 2) ? Wl : Wr;
        const int kb = (c & 1) << 6;

        __syncthreads();   // previous chunk fully consumed
        const int gn = bn + sn;
#pragma unroll
        for (int it = 0; it < 4; ++it) {
            float4 v = make_float4(0.f, 0.f, 0.f, 0.f);
            if (gn < N)
                v = *reinterpret_cast<const float4*>(&A[(size_t)gn * D + kb + skb + it * 4]);
            *reinterpret_cast<float4*>(&a_s[sn][skb + it * 4]) = v;
        }
        __syncthreads();

#pragma unroll 4
        for (int kk = 0; kk < 64; kk += 4) {
            const float4 w0 = *reinterpret_cast<const float4*>(&W[(kb + kk + 0) * D + (jg << 2)]);
            const float4 w1 = *reinterpret_cast<const float4*>(&W[(kb + kk + 1) * D + (jg << 2)]);
            const float4 w2 = *reinterpret_cast<const float4*>(&W[(kb + kk + 2) * D + (jg << 2)]);
            const float4 w3 = *reinterpret_cast<const float4*>(&W[(kb + kk + 3) * D + (jg << 2)]);
#pragma unroll
            for (int i = 0; i < 8; ++i) {
                const float4 av = *reinterpret_cast<const float4*>(&a_s[(ng << 3) + i][kk]);
                acc[i][0] = fmaf(av.w, w3.x, fmaf(av.z, w2.x, fmaf(av.y, w1.x, fmaf(av.x, w0.x, acc[i][0]))));
                acc[i][1] = fmaf(av.w, w3.y, fmaf(av.z, w2.y, fmaf(av.y, w1.y, fmaf(av.x, w0.y, acc[i][1]))));
                acc[i][2] = fmaf(av.w, w3.z, fmaf(av.z, w2.z, fmaf(av.y, w1.z, fmaf(av.x, w0.z, acc[i][2]))));
                acc[i][3] = fmaf(av.w, w3.w, fmaf(av.z, w2.w, fmaf(av.y, w1.w, fmaf(av.x, w0.w, acc[i][3]))));
            }
        }
    }

    // epilogue: bias, L1 norm across the 32 jg-lanes (each holds 4 features)
    const float4 bl4 = *reinterpret_cast<const float4*>(&bl[jg << 2]);
    const float4 br4 = *reinterpret_cast<const float4*>(&br[jg << 2]);
    const float bx = bl4.x + br4.x, by = bl4.y + br4.y,
                bz = bl4.z + br4.z, bw = bl4.w + br4.w;

#pragma unroll
    for (int i = 0; i < 8; ++i) {
        const float v0 = acc[i][0] + bx;
        const float v1 = acc[i][1] + by;
        const float v2 = acc[i][2] + bz;
        const float v3 = acc[i][3] + bw;
        float s = fabsf(v0) + fabsf(v1) + fabsf(v2) + fabsf(v3);
        // reduce across the 32 lanes holding this node's 128 features
        // (xor masks 1..16 stay within each 32-lane half of the wave)
#pragma unroll
        for (int m = 1; m < 32; m <<= 1) s += __shfl_xor(s, m, 64);
        s = fmaxf(s, 1e-12f);
        const float r = 1.0f / s;
        const int n = bn + (ng << 3) + i;
        if (n < N) {
            const float4 o = make_float4(v0 * r, v1 * r, v2 * r, v3 * r);
            *reinterpret_cast<float4*>(&out[(size_t)n * D + (jg << 2)]) = o;
        }
    }
}

extern "C" void kernel_launch(void* const* d_in, const int* in_sizes, int n_in,
                              void* d_out, int out_size, void* d_ws, size_t ws_size,
                              hipStream_t stream) {
    const float* x    = (const float*)d_in[0];
    const int*   esrc = (const int*)  d_in[1];
    const int*   edst = (const int*)  d_in[2];
    const float* ew   = (const float*)d_in[3];
    const float* Wl   = (const float*)d_in[4];
    const float* bl   = (const float*)d_in[5];
    const float* Wr   = (const float*)d_in[6];
    const float* br   = (const float*)d_in[7];
    float* out = (float*)d_out;

    const int N = in_sizes[0] / D;
    const int E = in_sizes[1];

    // agg lives in d_out; zero it first
    hipMemsetAsync(out, 0, (size_t)N * D * sizeof(float), stream);

    sage_scatter<<<2048, 256, 0, stream>>>(x, esrc, edst, ew, out, E);

    const int nb = (N + 63) / 64;
    sage_linear_norm<<<nb, 256, 0, stream>>>(out, x, Wl, bl, Wr, br, out, N);
}

// Round 2
// 626.800 us; speedup vs baseline: 2.2616x; 2.2616x over previous
//
#include <hip/hip_runtime.h>

// SAGEConv: agg = segment_sum(x[src]*w, dst); out = agg@W_l + b_l + x@W_r + b_r;
// out /= max(sum|out|, 1e-12) row-wise.  N=100000, E=1600000, D=128.
//
// Strategy (R2): kill the 1.3ms atomic scatter. Build CSR-by-dst in d_ws
// (histogram + 1-block scan + cursor fill), then gather-aggregate one wave
// per node with zero fp32 atomics and a single clean agg-row write.

static constexpr int D = 128;

// ---------------- CSR build ----------------
__global__ __launch_bounds__(256) void edge_count(
    const int* __restrict__ edst, int* __restrict__ cnt, int E)
{
    int i = blockIdx.x * blockDim.x + threadIdx.x;
    int stride = gridDim.x * blockDim.x;
    for (int e = i; e < E; e += stride)
        atomicAdd(&cnt[edst[e]], 1);
}

// single-workgroup exclusive scan of cnt[0..n) -> offs[0..n]
__global__ __launch_bounds__(1024) void scan_offsets(
    const int* __restrict__ cnt, int* __restrict__ offs, int n)
{
    __shared__ int sums[1024];
    const int tid = threadIdx.x;
    const int per = (n + 1023) / 1024;
    const int beg = tid * per;
    const int end = min(beg + per, n);
    int s = 0;
    for (int i = beg; i < end; ++i) s += cnt[i];
    sums[tid] = s;
    __syncthreads();
    int own = s;
    for (int off = 1; off < 1024; off <<= 1) {
        int t = (tid >= off) ? sums[tid - off] : 0;
        __syncthreads();
        sums[tid] += t;
        __syncthreads();
    }
    int run = sums[tid] - own;   // exclusive base for this thread's segment
    for (int i = beg; i < end; ++i) { offs[i] = run; run += cnt[i]; }
    if (end >= n) offs[n] = run; // all tail threads write the same total
}

__global__ __launch_bounds__(256) void edge_fill(
    const int* __restrict__ edst, int* cursor, int* __restrict__ perm, int E)
{
    int i = blockIdx.x * blockDim.x + threadIdx.x;
    int stride = gridDim.x * blockDim.x;
    for (int e = i; e < E; e += stride) {
        int pos = atomicAdd(&cursor[edst[e]], 1);
        perm[pos] = e;
    }
}

// ---------------- gather-aggregate: one wave per node ----------------
__global__ __launch_bounds__(256) void sage_gather(
    const float* __restrict__ x,
    const int* __restrict__ esrc,
    const float* __restrict__ ew,
    const int* __restrict__ offs,
    const int* __restrict__ perm,
    float* __restrict__ agg,
    int N)
{
    const int node = (blockIdx.x * blockDim.x + threadIdx.x) >> 6;
    const int lane = threadIdx.x & 63;
    if (node >= N) return;
    const int beg = offs[node];
    const int end = offs[node + 1];
    const float2* __restrict__ x2 = reinterpret_cast<const float2*>(x);

    float ax = 0.f, ay = 0.f;
    for (int base = beg; base < end; base += 64) {
        const int c = min(64, end - base);
        int s = 0; float w = 0.f;
        if (lane < c) {
            const int e = perm[base + lane];
            s = esrc[e];
            w = ew[e];
        }
        for (int k = 0; k < c; ++k) {
            const int sk = __shfl(s, k, 64);
            const float wk = __shfl(w, k, 64);
            const float2 xv = x2[(size_t)sk * 64 + lane];
            ax = fmaf(xv.x, wk, ax);
            ay = fmaf(xv.y, wk, ay);
        }
    }
    reinterpret_cast<float2*>(agg)[(size_t)node * 64 + lane] = make_float2(ax, ay);
}

// ---------------- fallback atomic scatter (ws too small) ----------------
__global__ __launch_bounds__(256) void sage_scatter(
    const float* __restrict__ x,
    const int* __restrict__ esrc,
    const int* __restrict__ edst,
    const float* __restrict__ ew,
    float* agg, int E)
{
    const int lane = threadIdx.x & 63;
    const int warp = (blockIdx.x * blockDim.x + threadIdx.x) >> 6;
    const int nwarps = (gridDim.x * blockDim.x) >> 6;
    const float2* __restrict__ x2 = reinterpret_cast<const float2*>(x);
    for (int e = warp; e < E; e += nwarps) {
        const int s = esrc[e];
        const int d = edst[e];
        const float w = ew[e];
        const float2 xv = x2[s * 64 + lane];
        atomicAdd(&agg[d * D + lane * 2 + 0], xv.x * w);
        atomicAdd(&agg[d * D + lane * 2 + 1], xv.y * w);
    }
}

// ------------- fused linear(l)+linear(r)+bias+L1-normalize -------------
__global__ __launch_bounds__(256) void sage_linear_norm(
    const float* agg,    // aliases out (d_out) — block-row-disjoint in-place
    const float* __restrict__ x,
    const float* __restrict__ Wl,
    const float* __restrict__ bl,
    const float* __restrict__ Wr,
    const float* __restrict__ br,
    float* out,
    int N)
{
    __shared__ float a_s[64][68];
    const int tid = threadIdx.x;
    const int jg = tid & 31;
    const int ng = tid >> 5;
    const int bn = blockIdx.x * 64;

    float acc[8][4];
#pragma unroll
    for (int i = 0; i < 8; ++i) {
        acc[i][0] = 0.f; acc[i][1] = 0.f; acc[i][2] = 0.f; acc[i][3] = 0.f;
    }

    const int sn  = tid >> 2;
    const int skb = (tid & 3) << 4;

    for (int c = 0; c < 4; ++c) {
        const float* A = (c < 2) ? agg : x;
        const float* __restrict__ W = (c < 2) ? Wl : Wr;
        const int kb = (c & 1) << 6;

        __syncthreads();
        const int gn = bn + sn;
#pragma unroll
        for (int it = 0; it < 4; ++it) {
            float4 v = make_float4(0.f, 0.f, 0.f, 0.f);
            if (gn < N)
                v = *reinterpret_cast<const float4*>(&A[(size_t)gn * D + kb + skb + it * 4]);
            *reinterpret_cast<float4*>(&a_s[sn][skb + it * 4]) = v;
        }
        __syncthreads();

#pragma unroll 4
        for (int kk = 0; kk < 64; kk += 4) {
            const float4 w0 = *reinterpret_cast<const float4*>(&W[(kb + kk + 0) * D + (jg << 2)]);
            const float4 w1 = *reinterpret_cast<const float4*>(&W[(kb + kk + 1) * D + (jg << 2)]);
            const float4 w2 = *reinterpret_cast<const float4*>(&W[(kb + kk + 2) * D + (jg << 2)]);
            const float4 w3 = *reinterpret_cast<const float4*>(&W[(kb + kk + 3) * D + (jg << 2)]);
#pragma unroll
            for (int i = 0; i < 8; ++i) {
                const float4 av = *reinterpret_cast<const float4*>(&a_s[(ng << 3) + i][kk]);
                acc[i][0] = fmaf(av.w, w3.x, fmaf(av.z, w2.x, fmaf(av.y, w1.x, fmaf(av.x, w0.x, acc[i][0]))));
                acc[i][1] = fmaf(av.w, w3.y, fmaf(av.z, w2.y, fmaf(av.y, w1.y, fmaf(av.x, w0.y, acc[i][1]))));
                acc[i][2] = fmaf(av.w, w3.z, fmaf(av.z, w2.z, fmaf(av.y, w1.z, fmaf(av.x, w0.z, acc[i][2]))));
                acc[i][3] = fmaf(av.w, w3.w, fmaf(av.z, w2.w, fmaf(av.y, w1.w, fmaf(av.x, w0.w, acc[i][3]))));
            }
        }
    }

    const float4 bl4 = *reinterpret_cast<const float4*>(&bl[jg << 2]);
    const float4 br4 = *reinterpret_cast<const float4*>(&br[jg << 2]);
    const float bx = bl4.x + br4.x, by = bl4.y + br4.y,
                bz = bl4.z + br4.z, bw = bl4.w + br4.w;

#pragma unroll
    for (int i = 0; i < 8; ++i) {
        const float v0 = acc[i][0] + bx;
        const float v1 = acc[i][1] + by;
        const float v2 = acc[i][2] + bz;
        const float v3 = acc[i][3] + bw;
        float s = fabsf(v0) + fabsf(v1) + fabsf(v2) + fabsf(v3);
#pragma unroll
        for (int m = 1; m < 32; m <<= 1) s += __shfl_xor(s, m, 64);
        s = fmaxf(s, 1e-12f);
        const float r = 1.0f / s;
        const int n = bn + (ng << 3) + i;
        if (n < N) {
            const float4 o = make_float4(v0 * r, v1 * r, v2 * r, v3 * r);
            *reinterpret_cast<float4*>(&out[(size_t)n * D + (jg << 2)]) = o;
        }
    }
}

extern "C" void kernel_launch(void* const* d_in, const int* in_sizes, int n_in,
                              void* d_out, int out_size, void* d_ws, size_t ws_size,
                              hipStream_t stream) {
    const float* x    = (const float*)d_in[0];
    const int*   esrc = (const int*)  d_in[1];
    const int*   edst = (const int*)  d_in[2];
    const float* ew   = (const float*)d_in[3];
    const float* Wl   = (const float*)d_in[4];
    const float* bl   = (const float*)d_in[5];
    const float* Wr   = (const float*)d_in[6];
    const float* br   = (const float*)d_in[7];
    float* out = (float*)d_out;

    const int N = in_sizes[0] / D;
    const int E = in_sizes[1];

    // ws layout: cnt[N+1] | offs[N+1] | cursor[N] | perm[E]  (256B aligned)
    auto align256 = [](size_t v) { return (v + 255) & ~size_t(255); };
    size_t off_cnt    = 0;
    size_t off_offs   = align256(off_cnt  + (size_t)(N + 1) * 4);
    size_t off_cursor = align256(off_offs + (size_t)(N + 1) * 4);
    size_t off_perm   = align256(off_cursor + (size_t)N * 4);
    size_t need       = off_perm + (size_t)E * 4;

    if (ws_size >= need) {
        char* ws = (char*)d_ws;
        int* cnt    = (int*)(ws + off_cnt);
        int* offs   = (int*)(ws + off_offs);
        int* cursor = (int*)(ws + off_cursor);
        int* perm   = (int*)(ws + off_perm);

        hipMemsetAsync(cnt, 0, (size_t)N * 4, stream);
        edge_count<<<2048, 256, 0, stream>>>(edst, cnt, E);
        scan_offsets<<<1, 1024, 0, stream>>>(cnt, offs, N);
        hipMemcpyAsync(cursor, offs, (size_t)N * 4, hipMemcpyDeviceToDevice, stream);
        edge_fill<<<2048, 256, 0, stream>>>(edst, cursor, perm, E);

        const int gb = (N * 64 + 255) / 256;   // one wave per node
        sage_gather<<<gb, 256, 0, stream>>>(x, esrc, ew, offs, perm, out, N);
    } else {
        // fallback: atomic scatter into d_out
        hipMemsetAsync(out, 0, (size_t)N * D * sizeof(float), stream);
        sage_scatter<<<2048, 256, 0, stream>>>(x, esrc, edst, ew, out, E);
    }

    const int nb = (N + 63) / 64;
    sage_linear_norm<<<nb, 256, 0, stream>>>(out, x, Wl, bl, Wr, br, out, N);
}

// Round 3
// 511.461 us; speedup vs baseline: 2.7716x; 1.2255x over previous
//
#include <hip/hip_runtime.h>
#include <hip/hip_fp16.h>

// SAGEConv: agg = segment_sum(x[src]*w, dst); out = agg@W_l + b_l + x@W_r + b_r;
// out /= max(sum|out|, 1e-12) row-wise.  N=100000, E=1600000, D=128.
//
// R3: (1) stage x as fp16 (halves gather traffic 819->410 MB logical),
//     (2) CSR fill writes packed (src,w) pairs -> gather edge stream is
//         linear + scalar (readfirstlane) with unroll-4 load pipelining,
//     (3) int4-vectorized scan.

static constexpr int D = 128;

// ---------------- x -> fp16 staging ----------------
__global__ __launch_bounds__(256) void cvt_x_fp16(
    const float4* __restrict__ x4, __half2* __restrict__ xh2, int n4)
{
    int i = blockIdx.x * blockDim.x + threadIdx.x;
    int stride = gridDim.x * blockDim.x;
    for (; i < n4; i += stride) {
        float4 v = x4[i];
        xh2[2 * i + 0] = __floats2half2_rn(v.x, v.y);
        xh2[2 * i + 1] = __floats2half2_rn(v.z, v.w);
    }
}

// ---------------- CSR build ----------------
__global__ __launch_bounds__(256) void edge_count(
    const int* __restrict__ edst, int* __restrict__ cnt, int E)
{
    int i = blockIdx.x * blockDim.x + threadIdx.x;
    int stride = gridDim.x * blockDim.x;
    for (int e = i; e < E; e += stride)
        atomicAdd(&cnt[edst[e]], 1);
}

// single-workgroup exclusive scan of cnt[0..n) -> offs[0..n]
__global__ __launch_bounds__(1024) void scan_offsets(
    const int* __restrict__ cnt, int* __restrict__ offs, int n)
{
    __shared__ int sums[1024];
    const int tid = threadIdx.x;
    const int per = (((n + 1023) >> 10) + 3) & ~3;  // multiple of 4
    const int beg = tid * per;
    const int end = min(beg + per, n);
    int s = 0;
    int i = beg;
    for (; i + 4 <= end; i += 4) {
        int4 v = *reinterpret_cast<const int4*>(&cnt[i]);
        s += v.x + v.y + v.z + v.w;
    }
    for (; i < end; ++i) s += cnt[i];
    sums[tid] = s;
    __syncthreads();
    const int own = s;
    for (int off = 1; off < 1024; off <<= 1) {
        int t = (tid >= off) ? sums[tid - off] : 0;
        __syncthreads();
        sums[tid] += t;
        __syncthreads();
    }
    int run = sums[tid] - own;   // exclusive base
    for (i = beg; i < end; ++i) { offs[i] = run; run += cnt[i]; }
    if (end >= n) offs[n] = run; // tail threads all hold the grand total
}

// fill packed (src, w_bits) pairs in CSR-bucket order
__global__ __launch_bounds__(256) void edge_fill(
    const int* __restrict__ esrc, const int* __restrict__ edst,
    const float* __restrict__ ew,
    int* cursor, int2* __restrict__ pairs, int E)
{
    int i = blockIdx.x * blockDim.x + threadIdx.x;
    int stride = gridDim.x * blockDim.x;
    for (int e = i; e < E; e += stride) {
        int pos = atomicAdd(&cursor[edst[e]], 1);
        pairs[pos] = make_int2(esrc[e], __float_as_int(ew[e]));
    }
}

// ---------------- gather-aggregate: one wave per node ----------------
// FP16X: x staged as fp16 (half2 per lane, 256B/row); else fp32 float2.
template <bool FP16X>
__global__ __launch_bounds__(256) void sage_gather(
    const void* __restrict__ xrows,
    const int2* __restrict__ pairs,
    const int* __restrict__ offs,
    float* __restrict__ agg,
    int N)
{
    int node = (blockIdx.x * blockDim.x + threadIdx.x) >> 6;
    const int lane = threadIdx.x & 63;
    if (node >= N) return;
    node = __builtin_amdgcn_readfirstlane(node);   // provably wave-uniform
    const int beg = offs[node];
    const int end = offs[node + 1];

    const __half2* __restrict__ xh = (const __half2*)xrows;
    const float2*  __restrict__ xf = (const float2*)xrows;

    float ax0 = 0.f, ay0 = 0.f, ax1 = 0.f, ay1 = 0.f;
    int k = beg;
    for (; k + 4 <= end; k += 4) {
        const int2 p0 = pairs[k + 0];
        const int2 p1 = pairs[k + 1];
        const int2 p2 = pairs[k + 2];
        const int2 p3 = pairs[k + 3];
        float2 v0, v1, v2, v3;
        if (FP16X) {
            v0 = __half22float2(xh[(size_t)p0.x * 64 + lane]);
            v1 = __half22float2(xh[(size_t)p1.x * 64 + lane]);
            v2 = __half22float2(xh[(size_t)p2.x * 64 + lane]);
            v3 = __half22float2(xh[(size_t)p3.x * 64 + lane]);
        } else {
            v0 = xf[(size_t)p0.x * 64 + lane];
            v1 = xf[(size_t)p1.x * 64 + lane];
            v2 = xf[(size_t)p2.x * 64 + lane];
            v3 = xf[(size_t)p3.x * 64 + lane];
        }
        const float w0 = __int_as_float(p0.y), w1 = __int_as_float(p1.y);
        const float w2 = __int_as_float(p2.y), w3 = __int_as_float(p3.y);
        ax0 = fmaf(v0.x, w0, ax0); ay0 = fmaf(v0.y, w0, ay0);
        ax1 = fmaf(v1.x, w1, ax1); ay1 = fmaf(v1.y, w1, ay1);
        ax0 = fmaf(v2.x, w2, ax0); ay0 = fmaf(v2.y, w2, ay0);
        ax1 = fmaf(v3.x, w3, ax1); ay1 = fmaf(v3.y, w3, ay1);
    }
    for (; k < end; ++k) {
        const int2 p = pairs[k];
        const float w = __int_as_float(p.y);
        float2 v;
        if (FP16X) v = __half22float2(xh[(size_t)p.x * 64 + lane]);
        else       v = xf[(size_t)p.x * 64 + lane];
        ax0 = fmaf(v.x, w, ax0); ay0 = fmaf(v.y, w, ay0);
    }
    reinterpret_cast<float2*>(agg)[(size_t)node * 64 + lane] =
        make_float2(ax0 + ax1, ay0 + ay1);
}

// ---------------- fallback atomic scatter (ws too small) ----------------
__global__ __launch_bounds__(256) void sage_scatter(
    const float* __restrict__ x,
    const int* __restrict__ esrc,
    const int* __restrict__ edst,
    const float* __restrict__ ew,
    float* agg, int E)
{
    const int lane = threadIdx.x & 63;
    const int warp = (blockIdx.x * blockDim.x + threadIdx.x) >> 6;
    const int nwarps = (gridDim.x * blockDim.x) >> 6;
    const float2* __restrict__ x2 = reinterpret_cast<const float2*>(x);
    for (int e = warp; e < E; e += nwarps) {
        const int s = esrc[e];
        const int d = edst[e];
        const float w = ew[e];
        const float2 xv = x2[s * 64 + lane];
        atomicAdd(&agg[d * D + lane * 2 + 0], xv.x * w);
        atomicAdd(&agg[d * D + lane * 2 + 1], xv.y * w);
    }
}

// ------------- fused linear(l)+linear(r)+bias+L1-normalize -------------
__global__ __launch_bounds__(256) void sage_linear_norm(
    const float* agg,    // aliases out (d_out) — block-row-disjoint in-place
    const float* __restrict__ x,
    const float* __restrict__ Wl,
    const float* __restrict__ bl,
    const float* __restrict__ Wr,
    const float* __restrict__ br,
    float* out,
    int N)
{
    __shared__ float a_s[64][68];
    const int tid = threadIdx.x;
    const int jg = tid & 31;
    const int ng = tid >> 5;
    const int bn = blockIdx.x * 64;

    float acc[8][4];
#pragma unroll
    for (int i = 0; i < 8; ++i) {
        acc[i][0] = 0.f; acc[i][1] = 0.f; acc[i][2] = 0.f; acc[i][3] = 0.f;
    }

    const int sn  = tid >> 2;
    const int skb = (tid & 3) << 4;

    for (int c = 0; c < 4; ++c) {
        const float* A = (c < 2) ? agg : x;
        const float* __restrict__ W = (c < 2) ? Wl : Wr;
        const int kb = (c & 1) << 6;

        __syncthreads();
        const int gn = bn + sn;
#pragma unroll
        for (int it = 0; it < 4; ++it) {
            float4 v = make_float4(0.f, 0.f, 0.f, 0.f);
            if (gn < N)
                v = *reinterpret_cast<const float4*>(&A[(size_t)gn * D + kb + skb + it * 4]);
            *reinterpret_cast<float4*>(&a_s[sn][skb + it * 4]) = v;
        }
        __syncthreads();

#pragma unroll 4
        for (int kk = 0; kk < 64; kk += 4) {
            const float4 w0 = *reinterpret_cast<const float4*>(&W[(kb + kk + 0) * D + (jg << 2)]);
            const float4 w1 = *reinterpret_cast<const float4*>(&W[(kb + kk + 1) * D + (jg << 2)]);
            const float4 w2 = *reinterpret_cast<const float4*>(&W[(kb + kk + 2) * D + (jg << 2)]);
            const float4 w3 = *reinterpret_cast<const float4*>(&W[(kb + kk + 3) * D + (jg << 2)]);
#pragma unroll
            for (int i = 0; i < 8; ++i) {
                const float4 av = *reinterpret_cast<const float4*>(&a_s[(ng << 3) + i][kk]);
                acc[i][0] = fmaf(av.w, w3.x, fmaf(av.z, w2.x, fmaf(av.y, w1.x, fmaf(av.x, w0.x, acc[i][0]))));
                acc[i][1] = fmaf(av.w, w3.y, fmaf(av.z, w2.y, fmaf(av.y, w1.y, fmaf(av.x, w0.y, acc[i][1]))));
                acc[i][2] = fmaf(av.w, w3.z, fmaf(av.z, w2.z, fmaf(av.y, w1.z, fmaf(av.x, w0.z, acc[i][2]))));
                acc[i][3] = fmaf(av.w, w3.w, fmaf(av.z, w2.w, fmaf(av.y, w1.w, fmaf(av.x, w0.w, acc[i][3]))));
            }
        }
    }

    const float4 bl4 = *reinterpret_cast<const float4*>(&bl[jg << 2]);
    const float4 br4 = *reinterpret_cast<const float4*>(&br[jg << 2]);
    const float bx = bl4.x + br4.x, by = bl4.y + br4.y,
                bz = bl4.z + br4.z, bw = bl4.w + br4.w;

#pragma unroll
    for (int i = 0; i < 8; ++i) {
        const float v0 = acc[i][0] + bx;
        const float v1 = acc[i][1] + by;
        const float v2 = acc[i][2] + bz;
        const float v3 = acc[i][3] + bw;
        float s = fabsf(v0) + fabsf(v1) + fabsf(v2) + fabsf(v3);
#pragma unroll
        for (int m = 1; m < 32; m <<= 1) s += __shfl_xor(s, m, 64);
        s = fmaxf(s, 1e-12f);
        const float r = 1.0f / s;
        const int n = bn + (ng << 3) + i;
        if (n < N) {
            const float4 o = make_float4(v0 * r, v1 * r, v2 * r, v3 * r);
            *reinterpret_cast<float4*>(&out[(size_t)n * D + (jg << 2)]) = o;
        }
    }
}

extern "C" void kernel_launch(void* const* d_in, const int* in_sizes, int n_in,
                              void* d_out, int out_size, void* d_ws, size_t ws_size,
                              hipStream_t stream) {
    const float* x    = (const float*)d_in[0];
    const int*   esrc = (const int*)  d_in[1];
    const int*   edst = (const int*)  d_in[2];
    const float* ew   = (const float*)d_in[3];
    const float* Wl   = (const float*)d_in[4];
    const float* bl   = (const float*)d_in[5];
    const float* Wr   = (const float*)d_in[6];
    const float* br   = (const float*)d_in[7];
    float* out = (float*)d_out;

    const int N = in_sizes[0] / D;
    const int E = in_sizes[1];

    // ws layout: cnt[N+1] | offs[N+1] | cursor[N] | pairs[E]x8B | xh[N*128]x2B
    auto align256 = [](size_t v) { return (v + 255) & ~size_t(255); };
    size_t off_cnt    = 0;
    size_t off_offs   = align256(off_cnt    + (size_t)(N + 1) * 4);
    size_t off_cursor = align256(off_offs   + (size_t)(N + 1) * 4);
    size_t off_pairs  = align256(off_cursor + (size_t)N * 4);
    size_t off_xh     = align256(off_pairs  + (size_t)E * 8);
    size_t need_b     = off_xh;                       // tier B: no fp16 x
    size_t need_a     = off_xh + (size_t)N * D * 2;   // tier A: + fp16 x

    if (ws_size >= need_b) {
        char* ws = (char*)d_ws;
        int*  cnt    = (int*) (ws + off_cnt);
        int*  offs   = (int*) (ws + off_offs);
        int*  cursor = (int*) (ws + off_cursor);
        int2* pairs  = (int2*)(ws + off_pairs);
        __half2* xh  = (__half2*)(ws + off_xh);

        const bool fp16x = (ws_size >= need_a);

        hipMemsetAsync(cnt, 0, (size_t)N * 4, stream);
        if (fp16x) {
            const int n4 = N * (D / 4);
            cvt_x_fp16<<<4096, 256, 0, stream>>>((const float4*)x, xh, n4);
        }
        edge_count<<<2048, 256, 0, stream>>>(edst, cnt, E);
        scan_offsets<<<1, 1024, 0, stream>>>(cnt, offs, N);
        hipMemcpyAsync(cursor, offs, (size_t)N * 4, hipMemcpyDeviceToDevice, stream);
        edge_fill<<<2048, 256, 0, stream>>>(esrc, edst, ew, cursor, pairs, E);

        const int gb = (N * 64 + 255) / 256;   // one wave per node
        if (fp16x)
            sage_gather<true ><<<gb, 256, 0, stream>>>(xh, pairs, offs, out, N);
        else
            sage_gather<false><<<gb, 256, 0, stream>>>(x,  pairs, offs, out, N);
    } else {
        hipMemsetAsync(out, 0, (size_t)N * D * sizeof(float), stream);
        sage_scatter<<<2048, 256, 0, stream>>>(x, esrc, edst, ew, out, E);
    }

    const int nb = (N + 63) / 64;
    sage_linear_norm<<<nb, 256, 0, stream>>>(out, x, Wl, bl, Wr, br, out, N);
}

// Round 4
// 241.771 us; speedup vs baseline: 5.8633x; 2.1155x over previous
//
#include <hip/hip_runtime.h>
#include <hip/hip_fp16.h>

// SAGEConv: agg = segment_sum(x[src]*w, dst); out = agg@W_l + b_l + x@W_r + b_r;
// out /= max(sum|out|, 1e-12) row-wise.  N=100000, E=1600000, D=128.
//
// R4: replace atomic CSR build (count 1.6M dev-atomics + serial scan + fill
// with 8x write-amplified scatter, ~300us) with a two-level counting sort:
//   coarse_count (LDS hist, 1024 bins of dst>>7) -> coarse_scan (1024-wide)
//   -> coarse_partition (per-block region reservation, bin-clustered writes)
//   -> fine_sort (one block per bucket: LDS 128-bin hist+scan, writes offs[]
//      and final (src,w) pairs into a contiguous 16KB region).
// Gather (fp16 x) and fused linear+L1norm unchanged.

static constexpr int D = 128;
static constexpr int NB = 1024;     // coarse buckets
static constexpr int CBITS = 7;     // nodes per bucket = 128
static constexpr int CSZ = 1 << CBITS;

// ---------------- x -> fp16 staging ----------------
__global__ __launch_bounds__(256) void cvt_x_fp16(
    const float4* __restrict__ x4, __half2* __restrict__ xh2, int n4)
{
    int i = blockIdx.x * blockDim.x + threadIdx.x;
    int stride = gridDim.x * blockDim.x;
    for (; i < n4; i += stride) {
        float4 v = x4[i];
        xh2[2 * i + 0] = __floats2half2_rn(v.x, v.y);
        xh2[2 * i + 1] = __floats2half2_rn(v.z, v.w);
    }
}

// ---------------- two-level counting sort ----------------
__global__ __launch_bounds__(256) void coarse_count(
    const int* __restrict__ edst, int* __restrict__ ccnt, int E, int chunk)
{
    __shared__ int hist[NB];
    for (int t = threadIdx.x; t < NB; t += 256) hist[t] = 0;
    __syncthreads();
    const int beg = blockIdx.x * chunk;
    const int end = min(E, beg + chunk);
    for (int e = beg + threadIdx.x; e < end; e += 256)
        atomicAdd(&hist[edst[e] >> CBITS], 1);
    __syncthreads();
    for (int t = threadIdx.x; t < NB; t += 256) {
        const int c = hist[t];
        if (c) atomicAdd(&ccnt[t], c);
    }
}

// 1 block x NB threads: exclusive scan of coarse counts; init cursors; offs[N]=E
__global__ __launch_bounds__(NB) void coarse_scan(
    const int* __restrict__ ccnt, int* __restrict__ cbase,
    int* __restrict__ ccur, int* __restrict__ offs, int N, int E)
{
    __shared__ int s[NB];
    const int t = threadIdx.x;
    const int v = ccnt[t];
    s[t] = v;
    __syncthreads();
    for (int off = 1; off < NB; off <<= 1) {
        const int u = (t >= off) ? s[t - off] : 0;
        __syncthreads();
        s[t] += u;
        __syncthreads();
    }
    const int excl = s[t] - v;
    cbase[t] = excl;
    ccur[t]  = excl;
    if (t == NB - 1) { cbase[NB] = s[t]; offs[N] = E; }
}

// partition edges into coarse buckets; pair = (dst_low7<<20 | src, w_bits)
__global__ __launch_bounds__(256) void coarse_partition(
    const int* __restrict__ esrc, const int* __restrict__ edst,
    const float* __restrict__ ew, int* ccur,
    int2* __restrict__ cpairs, int E, int chunk)
{
    __shared__ int hist[NB];
    for (int t = threadIdx.x; t < NB; t += 256) hist[t] = 0;
    __syncthreads();
    const int beg = blockIdx.x * chunk;
    const int end = min(E, beg + chunk);
    for (int e = beg + threadIdx.x; e < end; e += 256)
        atomicAdd(&hist[edst[e] >> CBITS], 1);
    __syncthreads();
    for (int t = threadIdx.x; t < NB; t += 256) {
        const int c = hist[t];
        hist[t] = c ? atomicAdd(&ccur[t], c) : 0;   // hist becomes global cursor
    }
    __syncthreads();
    for (int e = beg + threadIdx.x; e < end; e += 256) {
        const int d = edst[e];
        const int pos = atomicAdd(&hist[d >> CBITS], 1);
        cpairs[pos] = make_int2(((d & (CSZ - 1)) << 20) | esrc[e],
                                __float_as_int(ew[e]));
    }
}

// one block per coarse bucket: fine 128-bin counting sort + offs[] write
__global__ __launch_bounds__(256) void fine_sort(
    const int2* __restrict__ cpairs, const int* __restrict__ cbase,
    int* __restrict__ offs, int2* __restrict__ pairs, int N)
{
    __shared__ int hist[CSZ];
    __shared__ int scn[CSZ];
    const int b = blockIdx.x;
    const int t = threadIdx.x;
    const int s0 = cbase[b], s1 = cbase[b + 1];
    if (t < CSZ) hist[t] = 0;
    __syncthreads();
    for (int i = s0 + t; i < s1; i += 256)
        atomicAdd(&hist[(cpairs[i].x >> 20) & (CSZ - 1)], 1);
    __syncthreads();
    if (t < CSZ) scn[t] = hist[t];
    __syncthreads();
    for (int off = 1; off < CSZ; off <<= 1) {
        int u = 0;
        if (t < CSZ && t >= off) u = scn[t - off];
        __syncthreads();
        if (t < CSZ) scn[t] += u;
        __syncthreads();
    }
    if (t < CSZ) {
        const int base = s0 + scn[t] - hist[t];   // exclusive
        const int node = (b << CBITS) + t;
        if (node < N) offs[node] = base;
        hist[t] = base;                            // becomes cursor
    }
    __syncthreads();
    for (int i = s0 + t; i < s1; i += 256) {
        const int2 p = cpairs[i];
        const int pos = atomicAdd(&hist[(p.x >> 20) & (CSZ - 1)], 1);
        pairs[pos] = make_int2(p.x & 0xFFFFF, p.y);
    }
}

// ---------------- gather-aggregate: one wave per node ----------------
template <bool FP16X>
__global__ __launch_bounds__(256) void sage_gather(
    const void* __restrict__ xrows,
    const int2* __restrict__ pairs,
    const int* __restrict__ offs,
    float* __restrict__ agg,
    int N)
{
    int node = (blockIdx.x * blockDim.x + threadIdx.x) >> 6;
    const int lane = threadIdx.x & 63;
    if (node >= N) return;
    node = __builtin_amdgcn_readfirstlane(node);
    const int beg = offs[node];
    const int end = offs[node + 1];

    const __half2* __restrict__ xh = (const __half2*)xrows;
    const float2*  __restrict__ xf = (const float2*)xrows;

    float ax0 = 0.f, ay0 = 0.f, ax1 = 0.f, ay1 = 0.f;
    int k = beg;
    for (; k + 4 <= end; k += 4) {
        const int2 p0 = pairs[k + 0];
        const int2 p1 = pairs[k + 1];
        const int2 p2 = pairs[k + 2];
        const int2 p3 = pairs[k + 3];
        float2 v0, v1, v2, v3;
        if (FP16X) {
            v0 = __half22float2(xh[(size_t)p0.x * 64 + lane]);
            v1 = __half22float2(xh[(size_t)p1.x * 64 + lane]);
            v2 = __half22float2(xh[(size_t)p2.x * 64 + lane]);
            v3 = __half22float2(xh[(size_t)p3.x * 64 + lane]);
        } else {
            v0 = xf[(size_t)p0.x * 64 + lane];
            v1 = xf[(size_t)p1.x * 64 + lane];
            v2 = xf[(size_t)p2.x * 64 + lane];
            v3 = xf[(size_t)p3.x * 64 + lane];
        }
        const float w0 = __int_as_float(p0.y), w1 = __int_as_float(p1.y);
        const float w2 = __int_as_float(p2.y), w3 = __int_as_float(p3.y);
        ax0 = fmaf(v0.x, w0, ax0); ay0 = fmaf(v0.y, w0, ay0);
        ax1 = fmaf(v1.x, w1, ax1); ay1 = fmaf(v1.y, w1, ay1);
        ax0 = fmaf(v2.x, w2, ax0); ay0 = fmaf(v2.y, w2, ay0);
        ax1 = fmaf(v3.x, w3, ax1); ay1 = fmaf(v3.y, w3, ay1);
    }
    for (; k < end; ++k) {
        const int2 p = pairs[k];
        const float w = __int_as_float(p.y);
        float2 v;
        if (FP16X) v = __half22float2(xh[(size_t)p.x * 64 + lane]);
        else       v = xf[(size_t)p.x * 64 + lane];
        ax0 = fmaf(v.x, w, ax0); ay0 = fmaf(v.y, w, ay0);
    }
    reinterpret_cast<float2*>(agg)[(size_t)node * 64 + lane] =
        make_float2(ax0 + ax1, ay0 + ay1);
}

// ---------------- fallback atomic scatter (ws too small) ----------------
__global__ __launch_bounds__(256) void sage_scatter(
    const float* __restrict__ x,
    const int* __restrict__ esrc,
    const int* __restrict__ edst,
    const float* __restrict__ ew,
    float* agg, int E)
{
    const int lane = threadIdx.x & 63;
    const int warp = (blockIdx.x * blockDim.x + threadIdx.x) >> 6;
    const int nwarps = (gridDim.x * blockDim.x) >> 6;
    const float2* __restrict__ x2 = reinterpret_cast<const float2*>(x);
    for (int e = warp; e < E; e += nwarps) {
        const int s = esrc[e];
        const int d = edst[e];
        const float w = ew[e];
        const float2 xv = x2[s * 64 + lane];
        atomicAdd(&agg[d * D + lane * 2 + 0], xv.x * w);
        atomicAdd(&agg[d * D + lane * 2 + 1], xv.y * w);
    }
}

// ------------- fused linear(l)+linear(r)+bias+L1-normalize -------------
__global__ __launch_bounds__(256) void sage_linear_norm(
    const float* agg,    // aliases out (d_out) — block-row-disjoint in-place
    const float* __restrict__ x,
    const float* __restrict__ Wl,
    const float* __restrict__ bl,
    const float* __restrict__ Wr,
    const float* __restrict__ br,
    float* out,
    int N)
{
    __shared__ float a_s[64][68];
    const int tid = threadIdx.x;
    const int jg = tid & 31;
    const int ng = tid >> 5;
    const int bn = blockIdx.x * 64;

    float acc[8][4];
#pragma unroll
    for (int i = 0; i < 8; ++i) {
        acc[i][0] = 0.f; acc[i][1] = 0.f; acc[i][2] = 0.f; acc[i][3] = 0.f;
    }

    const int sn  = tid >> 2;
    const int skb = (tid & 3) << 4;

    for (int c = 0; c < 4; ++c) {
        const float* A = (c < 2) ? agg : x;
        const float* __restrict__ W = (c < 2) ? Wl : Wr;
        const int kb = (c & 1) << 6;

        __syncthreads();
        const int gn = bn + sn;
#pragma unroll
        for (int it = 0; it < 4; ++it) {
            float4 v = make_float4(0.f, 0.f, 0.f, 0.f);
            if (gn < N)
                v = *reinterpret_cast<const float4*>(&A[(size_t)gn * D + kb + skb + it * 4]);
            *reinterpret_cast<float4*>(&a_s[sn][skb + it * 4]) = v;
        }
        __syncthreads();

#pragma unroll 4
        for (int kk = 0; kk < 64; kk += 4) {
            const float4 w0 = *reinterpret_cast<const float4*>(&W[(kb + kk + 0) * D + (jg << 2)]);
            const float4 w1 = *reinterpret_cast<const float4*>(&W[(kb + kk + 1) * D + (jg << 2)]);
            const float4 w2 = *reinterpret_cast<const float4*>(&W[(kb + kk + 2) * D + (jg << 2)]);
            const float4 w3 = *reinterpret_cast<const float4*>(&W[(kb + kk + 3) * D + (jg << 2)]);
#pragma unroll
            for (int i = 0; i < 8; ++i) {
                const float4 av = *reinterpret_cast<const float4*>(&a_s[(ng << 3) + i][kk]);
                acc[i][0] = fmaf(av.w, w3.x, fmaf(av.z, w2.x, fmaf(av.y, w1.x, fmaf(av.x, w0.x, acc[i][0]))));
                acc[i][1] = fmaf(av.w, w3.y, fmaf(av.z, w2.y, fmaf(av.y, w1.y, fmaf(av.x, w0.y, acc[i][1]))));
                acc[i][2] = fmaf(av.w, w3.z, fmaf(av.z, w2.z, fmaf(av.y, w1.z, fmaf(av.x, w0.z, acc[i][2]))));
                acc[i][3] = fmaf(av.w, w3.w, fmaf(av.z, w2.w, fmaf(av.y, w1.w, fmaf(av.x, w0.w, acc[i][3]))));
            }
        }
    }

    const float4 bl4 = *reinterpret_cast<const float4*>(&bl[jg << 2]);
    const float4 br4 = *reinterpret_cast<const float4*>(&br[jg << 2]);
    const float bx = bl4.x + br4.x, by = bl4.y + br4.y,
                bz = bl4.z + br4.z, bw = bl4.w + br4.w;

#pragma unroll
    for (int i = 0; i < 8; ++i) {
        const float v0 = acc[i][0] + bx;
        const float v1 = acc[i][1] + by;
        const float v2 = acc[i][2] + bz;
        const float v3 = acc[i][3] + bw;
        float s = fabsf(v0) + fabsf(v1) + fabsf(v2) + fabsf(v3);
#pragma unroll
        for (int m = 1; m < 32; m <<= 1) s += __shfl_xor(s, m, 64);
        s = fmaxf(s, 1e-12f);
        const float r = 1.0f / s;
        const int n = bn + (ng << 3) + i;
        if (n < N) {
            const float4 o = make_float4(v0 * r, v1 * r, v2 * r, v3 * r);
            *reinterpret_cast<float4*>(&out[(size_t)n * D + (jg << 2)]) = o;
        }
    }
}

extern "C" void kernel_launch(void* const* d_in, const int* in_sizes, int n_in,
                              void* d_out, int out_size, void* d_ws, size_t ws_size,
                              hipStream_t stream) {
    const float* x    = (const float*)d_in[0];
    const int*   esrc = (const int*)  d_in[1];
    const int*   edst = (const int*)  d_in[2];
    const float* ew   = (const float*)d_in[3];
    const float* Wl   = (const float*)d_in[4];
    const float* bl   = (const float*)d_in[5];
    const float* Wr   = (const float*)d_in[6];
    const float* br   = (const float*)d_in[7];
    float* out = (float*)d_out;

    const int N = in_sizes[0] / D;
    const int E = in_sizes[1];

    // ws: ccnt[NB] | cbase[NB+1] | ccur[NB] | offs[N+1] | cpairs[E] | pairs[E] | xh
    auto align256 = [](size_t v) { return (v + 255) & ~size_t(255); };
    size_t off_ccnt   = 0;
    size_t off_cbase  = align256(off_ccnt   + (size_t)NB * 4);
    size_t off_ccur   = align256(off_cbase  + (size_t)(NB + 1) * 4);
    size_t off_offs   = align256(off_ccur   + (size_t)NB * 4);
    size_t off_cpairs = align256(off_offs   + (size_t)(N + 1) * 4);
    size_t off_pairs  = align256(off_cpairs + (size_t)E * 8);
    size_t off_xh     = align256(off_pairs  + (size_t)E * 8);
    size_t need_b     = off_xh;                       // no fp16 x
    size_t need_a     = off_xh + (size_t)N * D * 2;   // + fp16 x

    const bool fits_meta = (N <= (1 << 20)) && ((N + CSZ - 1) >> CBITS) <= NB;

    if (ws_size >= need_b && fits_meta) {
        char* ws = (char*)d_ws;
        int*  ccnt   = (int*) (ws + off_ccnt);
        int*  cbase  = (int*) (ws + off_cbase);
        int*  ccur   = (int*) (ws + off_ccur);
        int*  offs   = (int*) (ws + off_offs);
        int2* cpairs = (int2*)(ws + off_cpairs);
        int2* pairs  = (int2*)(ws + off_pairs);
        __half2* xh  = (__half2*)(ws + off_xh);

        const bool fp16x = (ws_size >= need_a);
        const int chunk = (E + 255) / 256;
        const int nbu = (N + CSZ - 1) >> CBITS;

        hipMemsetAsync(ccnt, 0, (size_t)NB * 4, stream);
        if (fp16x)
            cvt_x_fp16<<<4096, 256, 0, stream>>>((const float4*)x, xh, N * (D / 4));

        coarse_count<<<256, 256, 0, stream>>>(edst, ccnt, E, chunk);
        coarse_scan<<<1, NB, 0, stream>>>(ccnt, cbase, ccur, offs, N, E);
        coarse_partition<<<256, 256, 0, stream>>>(esrc, edst, ew, ccur, cpairs, E, chunk);
        fine_sort<<<nbu, 256, 0, stream>>>(cpairs, cbase, offs, pairs, N);

        const int gb = (N * 64 + 255) / 256;   // one wave per node
        if (fp16x)
            sage_gather<true ><<<gb, 256, 0, stream>>>(xh, pairs, offs, out, N);
        else
            sage_gather<false><<<gb, 256, 0, stream>>>(x,  pairs, offs, out, N);
    } else {
        hipMemsetAsync(out, 0, (size_t)N * D * sizeof(float), stream);
        sage_scatter<<<2048, 256, 0, stream>>>(x, esrc, edst, ew, out, E);
    }

    const int nb = (N + 63) / 64;
    sage_linear_norm<<<nb, 256, 0, stream>>>(out, x, Wl, bl, Wr, br, out, N);
}

// Round 5
// 232.813 us; speedup vs baseline: 6.0889x; 1.0385x over previous
//
#include <hip/hip_runtime.h>
#include <hip/hip_fp16.h>

// SAGEConv: agg = segment_sum(x[src]*w, dst); out = agg@W_l + b_l + x@W_r + b_r;
// out /= max(sum|out|, 1e-12) row-wise.  N=100000, E=1600000, D=128.
//
// R5: sage_linear_norm was re-streaming W from global every kk-step
// (1.6 GB L2 traffic, VALUBusy 44%). Stage the per-chunk W tile [64][128]
// in LDS (cooperative coalesced loads, 128 KB/block total global W traffic)
// and read it via ds_read_b128. Sort/gather pipeline unchanged.

static constexpr int D = 128;
static constexpr int NB = 1024;     // coarse buckets
static constexpr int CBITS = 7;     // nodes per bucket = 128
static constexpr int CSZ = 1 << CBITS;

// ---------------- x -> fp16 staging ----------------
__global__ __launch_bounds__(256) void cvt_x_fp16(
    const float4* __restrict__ x4, __half2* __restrict__ xh2, int n4)
{
    int i = blockIdx.x * blockDim.x + threadIdx.x;
    int stride = gridDim.x * blockDim.x;
    for (; i < n4; i += stride) {
        float4 v = x4[i];
        xh2[2 * i + 0] = __floats2half2_rn(v.x, v.y);
        xh2[2 * i + 1] = __floats2half2_rn(v.z, v.w);
    }
}

// ---------------- two-level counting sort ----------------
__global__ __launch_bounds__(256) void coarse_count(
    const int* __restrict__ edst, int* __restrict__ ccnt, int E, int chunk)
{
    __shared__ int hist[NB];
    for (int t = threadIdx.x; t < NB; t += 256) hist[t] = 0;
    __syncthreads();
    const int beg = blockIdx.x * chunk;
    const int end = min(E, beg + chunk);
    for (int e = beg + threadIdx.x; e < end; e += 256)
        atomicAdd(&hist[edst[e] >> CBITS], 1);
    __syncthreads();
    for (int t = threadIdx.x; t < NB; t += 256) {
        const int c = hist[t];
        if (c) atomicAdd(&ccnt[t], c);
    }
}

// 1 block x NB threads: exclusive scan of coarse counts; init cursors; offs[N]=E
__global__ __launch_bounds__(NB) void coarse_scan(
    const int* __restrict__ ccnt, int* __restrict__ cbase,
    int* __restrict__ ccur, int* __restrict__ offs, int N, int E)
{
    __shared__ int s[NB];
    const int t = threadIdx.x;
    const int v = ccnt[t];
    s[t] = v;
    __syncthreads();
    for (int off = 1; off < NB; off <<= 1) {
        const int u = (t >= off) ? s[t - off] : 0;
        __syncthreads();
        s[t] += u;
        __syncthreads();
    }
    const int excl = s[t] - v;
    cbase[t] = excl;
    ccur[t]  = excl;
    if (t == NB - 1) { cbase[NB] = s[t]; offs[N] = E; }
}

// partition edges into coarse buckets; pair = (dst_low7<<20 | src, w_bits)
__global__ __launch_bounds__(256) void coarse_partition(
    const int* __restrict__ esrc, const int* __restrict__ edst,
    const float* __restrict__ ew, int* ccur,
    int2* __restrict__ cpairs, int E, int chunk)
{
    __shared__ int hist[NB];
    for (int t = threadIdx.x; t < NB; t += 256) hist[t] = 0;
    __syncthreads();
    const int beg = blockIdx.x * chunk;
    const int end = min(E, beg + chunk);
    for (int e = beg + threadIdx.x; e < end; e += 256)
        atomicAdd(&hist[edst[e] >> CBITS], 1);
    __syncthreads();
    for (int t = threadIdx.x; t < NB; t += 256) {
        const int c = hist[t];
        hist[t] = c ? atomicAdd(&ccur[t], c) : 0;   // hist becomes global cursor
    }
    __syncthreads();
    for (int e = beg + threadIdx.x; e < end; e += 256) {
        const int d = edst[e];
        const int pos = atomicAdd(&hist[d >> CBITS], 1);
        cpairs[pos] = make_int2(((d & (CSZ - 1)) << 20) | esrc[e],
                                __float_as_int(ew[e]));
    }
}

// one block per coarse bucket: fine 128-bin counting sort + offs[] write
__global__ __launch_bounds__(256) void fine_sort(
    const int2* __restrict__ cpairs, const int* __restrict__ cbase,
    int* __restrict__ offs, int2* __restrict__ pairs, int N)
{
    __shared__ int hist[CSZ];
    __shared__ int scn[CSZ];
    const int b = blockIdx.x;
    const int t = threadIdx.x;
    const int s0 = cbase[b], s1 = cbase[b + 1];
    if (t < CSZ) hist[t] = 0;
    __syncthreads();
    for (int i = s0 + t; i < s1; i += 256)
        atomicAdd(&hist[(cpairs[i].x >> 20) & (CSZ - 1)], 1);
    __syncthreads();
    if (t < CSZ) scn[t] = hist[t];
    __syncthreads();
    for (int off = 1; off < CSZ; off <<= 1) {
        int u = 0;
        if (t < CSZ && t >= off) u = scn[t - off];
        __syncthreads();
        if (t < CSZ) scn[t] += u;
        __syncthreads();
    }
    if (t < CSZ) {
        const int base = s0 + scn[t] - hist[t];   // exclusive
        const int node = (b << CBITS) + t;
        if (node < N) offs[node] = base;
        hist[t] = base;                            // becomes cursor
    }
    __syncthreads();
    for (int i = s0 + t; i < s1; i += 256) {
        const int2 p = cpairs[i];
        const int pos = atomicAdd(&hist[(p.x >> 20) & (CSZ - 1)], 1);
        pairs[pos] = make_int2(p.x & 0xFFFFF, p.y);
    }
}

// ---------------- gather-aggregate: one wave per node ----------------
template <bool FP16X>
__global__ __launch_bounds__(256) void sage_gather(
    const void* __restrict__ xrows,
    const int2* __restrict__ pairs,
    const int* __restrict__ offs,
    float* __restrict__ agg,
    int N)
{
    int node = (blockIdx.x * blockDim.x + threadIdx.x) >> 6;
    const int lane = threadIdx.x & 63;
    if (node >= N) return;
    node = __builtin_amdgcn_readfirstlane(node);
    const int beg = offs[node];
    const int end = offs[node + 1];

    const __half2* __restrict__ xh = (const __half2*)xrows;
    const float2*  __restrict__ xf = (const float2*)xrows;

    float ax0 = 0.f, ay0 = 0.f, ax1 = 0.f, ay1 = 0.f;
    int k = beg;
    for (; k + 4 <= end; k += 4) {
        const int2 p0 = pairs[k + 0];
        const int2 p1 = pairs[k + 1];
        const int2 p2 = pairs[k + 2];
        const int2 p3 = pairs[k + 3];
        float2 v0, v1, v2, v3;
        if (FP16X) {
            v0 = __half22float2(xh[(size_t)p0.x * 64 + lane]);
            v1 = __half22float2(xh[(size_t)p1.x * 64 + lane]);
            v2 = __half22float2(xh[(size_t)p2.x * 64 + lane]);
            v3 = __half22float2(xh[(size_t)p3.x * 64 + lane]);
        } else {
            v0 = xf[(size_t)p0.x * 64 + lane];
            v1 = xf[(size_t)p1.x * 64 + lane];
            v2 = xf[(size_t)p2.x * 64 + lane];
            v3 = xf[(size_t)p3.x * 64 + lane];
        }
        const float w0 = __int_as_float(p0.y), w1 = __int_as_float(p1.y);
        const float w2 = __int_as_float(p2.y), w3 = __int_as_float(p3.y);
        ax0 = fmaf(v0.x, w0, ax0); ay0 = fmaf(v0.y, w0, ay0);
        ax1 = fmaf(v1.x, w1, ax1); ay1 = fmaf(v1.y, w1, ay1);
        ax0 = fmaf(v2.x, w2, ax0); ay0 = fmaf(v2.y, w2, ay0);
        ax1 = fmaf(v3.x, w3, ax1); ay1 = fmaf(v3.y, w3, ay1);
    }
    for (; k < end; ++k) {
        const int2 p = pairs[k];
        const float w = __int_as_float(p.y);
        float2 v;
        if (FP16X) v = __half22float2(xh[(size_t)p.x * 64 + lane]);
        else       v = xf[(size_t)p.x * 64 + lane];
        ax0 = fmaf(v.x, w, ax0); ay0 = fmaf(v.y, w, ay0);
    }
    reinterpret_cast<float2*>(agg)[(size_t)node * 64 + lane] =
        make_float2(ax0 + ax1, ay0 + ay1);
}

// ---------------- fallback atomic scatter (ws too small) ----------------
__global__ __launch_bounds__(256) void sage_scatter(
    const float* __restrict__ x,
    const int* __restrict__ esrc,
    const int* __restrict__ edst,
    const float* __restrict__ ew,
    float* agg, int E)
{
    const int lane = threadIdx.x & 63;
    const int warp = (blockIdx.x * blockDim.x + threadIdx.x) >> 6;
    const int nwarps = (gridDim.x * blockDim.x) >> 6;
    const float2* __restrict__ x2 = reinterpret_cast<const float2*>(x);
    for (int e = warp; e < E; e += nwarps) {
        const int s = esrc[e];
        const int d = edst[e];
        const float w = ew[e];
        const float2 xv = x2[s * 64 + lane];
        atomicAdd(&agg[d * D + lane * 2 + 0], xv.x * w);
        atomicAdd(&agg[d * D + lane * 2 + 1], xv.y * w);
    }
}

// ------------- fused linear(l)+linear(r)+bias+L1-normalize -------------
// R5: W tile staged in LDS per chunk (was: 256 global float4 loads/thread).
__global__ __launch_bounds__(256) void sage_linear_norm(
    const float* agg,    // aliases out (d_out) — block-row-disjoint in-place
    const float* __restrict__ x,
    const float* __restrict__ Wl,
    const float* __restrict__ bl,
    const float* __restrict__ Wr,
    const float* __restrict__ br,
    float* out,
    int N)
{
    __shared__ float a_s[64][68];    // [node][k-chunk], +4 pad
    __shared__ float w_s[64][132];   // [k-chunk][col], +4 pad
    const int tid = threadIdx.x;
    const int jg = tid & 31;
    const int ng = tid >> 5;
    const int bn = blockIdx.x * 64;

    float acc[8][4];
#pragma unroll
    for (int i = 0; i < 8; ++i) {
        acc[i][0] = 0.f; acc[i][1] = 0.f; acc[i][2] = 0.f; acc[i][3] = 0.f;
    }

    const int sn  = tid >> 2;        // a-staging: node within tile
    const int skb = (tid & 3) << 4;  // a-staging: k offset base
    const int wr  = tid >> 5;        // w-staging: row stride-8 base (8 rows/iter)
    const int wc  = (tid & 31) << 2; // w-staging: col

    for (int c = 0; c < 4; ++c) {
        const float* A = (c < 2) ? agg : x;
        const float* __restrict__ W = (c < 2) ? Wl : Wr;
        const int kb = (c & 1) << 6;

        __syncthreads();   // previous chunk fully consumed
        const int gn = bn + sn;
#pragma unroll
        for (int it = 0; it < 4; ++it) {
            float4 v = make_float4(0.f, 0.f, 0.f, 0.f);
            if (gn < N)
                v = *reinterpret_cast<const float4*>(&A[(size_t)gn * D + kb + skb + it * 4]);
            *reinterpret_cast<float4*>(&a_s[sn][skb + it * 4]) = v;
        }
        // stage W rows kb..kb+63, all 128 cols: 8 iters x (8 rows x 128 cols)
#pragma unroll
        for (int it = 0; it < 8; ++it) {
            const int row = it * 8 + wr;
            const float4 v = *reinterpret_cast<const float4*>(&W[(size_t)(kb + row) * D + wc]);
            *reinterpret_cast<float4*>(&w_s[row][wc]) = v;
        }
        __syncthreads();

#pragma unroll 4
        for (int kk = 0; kk < 64; kk += 4) {
            const float4 w0 = *reinterpret_cast<const float4*>(&w_s[kk + 0][jg << 2]);
            const float4 w1 = *reinterpret_cast<const float4*>(&w_s[kk + 1][jg << 2]);
            const float4 w2 = *reinterpret_cast<const float4*>(&w_s[kk + 2][jg << 2]);
            const float4 w3 = *reinterpret_cast<const float4*>(&w_s[kk + 3][jg << 2]);
#pragma unroll
            for (int i = 0; i < 8; ++i) {
                const float4 av = *reinterpret_cast<const float4*>(&a_s[(ng << 3) + i][kk]);
                acc[i][0] = fmaf(av.w, w3.x, fmaf(av.z, w2.x, fmaf(av.y, w1.x, fmaf(av.x, w0.x, acc[i][0]))));
                acc[i][1] = fmaf(av.w, w3.y, fmaf(av.z, w2.y, fmaf(av.y, w1.y, fmaf(av.x, w0.y, acc[i][1]))));
                acc[i][2] = fmaf(av.w, w3.z, fmaf(av.z, w2.z, fmaf(av.y, w1.z, fmaf(av.x, w0.z, acc[i][2]))));
                acc[i][3] = fmaf(av.w, w3.w, fmaf(av.z, w2.w, fmaf(av.y, w1.w, fmaf(av.x, w0.w, acc[i][3]))));
            }
        }
    }

    const float4 bl4 = *reinterpret_cast<const float4*>(&bl[jg << 2]);
    const float4 br4 = *reinterpret_cast<const float4*>(&br[jg << 2]);
    const float bx = bl4.x + br4.x, by = bl4.y + br4.y,
                bz = bl4.z + br4.z, bw = bl4.w + br4.w;

#pragma unroll
    for (int i = 0; i < 8; ++i) {
        const float v0 = acc[i][0] + bx;
        const float v1 = acc[i][1] + by;
        const float v2 = acc[i][2] + bz;
        const float v3 = acc[i][3] + bw;
        float s = fabsf(v0) + fabsf(v1) + fabsf(v2) + fabsf(v3);
#pragma unroll
        for (int m = 1; m < 32; m <<= 1) s += __shfl_xor(s, m, 64);
        s = fmaxf(s, 1e-12f);
        const float r = 1.0f / s;
        const int n = bn + (ng << 3) + i;
        if (n < N) {
            const float4 o = make_float4(v0 * r, v1 * r, v2 * r, v3 * r);
            *reinterpret_cast<float4*>(&out[(size_t)n * D + (jg << 2)]) = o;
        }
    }
}

extern "C" void kernel_launch(void* const* d_in, const int* in_sizes, int n_in,
                              void* d_out, int out_size, void* d_ws, size_t ws_size,
                              hipStream_t stream) {
    const float* x    = (const float*)d_in[0];
    const int*   esrc = (const int*)  d_in[1];
    const int*   edst = (const int*)  d_in[2];
    const float* ew   = (const float*)d_in[3];
    const float* Wl   = (const float*)d_in[4];
    const float* bl   = (const float*)d_in[5];
    const float* Wr   = (const float*)d_in[6];
    const float* br   = (const float*)d_in[7];
    float* out = (float*)d_out;

    const int N = in_sizes[0] / D;
    const int E = in_sizes[1];

    // ws: ccnt[NB] | cbase[NB+1] | ccur[NB] | offs[N+1] | cpairs[E] | pairs[E] | xh
    auto align256 = [](size_t v) { return (v + 255) & ~size_t(255); };
    size_t off_ccnt   = 0;
    size_t off_cbase  = align256(off_ccnt   + (size_t)NB * 4);
    size_t off_ccur   = align256(off_cbase  + (size_t)(NB + 1) * 4);
    size_t off_offs   = align256(off_ccur   + (size_t)NB * 4);
    size_t off_cpairs = align256(off_offs   + (size_t)(N + 1) * 4);
    size_t off_pairs  = align256(off_cpairs + (size_t)E * 8);
    size_t off_xh     = align256(off_pairs  + (size_t)E * 8);
    size_t need_b     = off_xh;                       // no fp16 x
    size_t need_a     = off_xh + (size_t)N * D * 2;   // + fp16 x

    const bool fits_meta = (N <= (1 << 20)) && ((N + CSZ - 1) >> CBITS) <= NB;

    if (ws_size >= need_b && fits_meta) {
        char* ws = (char*)d_ws;
        int*  ccnt   = (int*) (ws + off_ccnt);
        int*  cbase  = (int*) (ws + off_cbase);
        int*  ccur   = (int*) (ws + off_ccur);
        int*  offs   = (int*) (ws + off_offs);
        int2* cpairs = (int2*)(ws + off_cpairs);
        int2* pairs  = (int2*)(ws + off_pairs);
        __half2* xh  = (__half2*)(ws + off_xh);

        const bool fp16x = (ws_size >= need_a);
        const int chunk = (E + 255) / 256;
        const int nbu = (N + CSZ - 1) >> CBITS;

        hipMemsetAsync(ccnt, 0, (size_t)NB * 4, stream);
        if (fp16x)
            cvt_x_fp16<<<4096, 256, 0, stream>>>((const float4*)x, xh, N * (D / 4));

        coarse_count<<<256, 256, 0, stream>>>(edst, ccnt, E, chunk);
        coarse_scan<<<1, NB, 0, stream>>>(ccnt, cbase, ccur, offs, N, E);
        coarse_partition<<<256, 256, 0, stream>>>(esrc, edst, ew, ccur, cpairs, E, chunk);
        fine_sort<<<nbu, 256, 0, stream>>>(cpairs, cbase, offs, pairs, N);

        const int gb = (N * 64 + 255) / 256;   // one wave per node
        if (fp16x)
            sage_gather<true ><<<gb, 256, 0, stream>>>(xh, pairs, offs, out, N);
        else
            sage_gather<false><<<gb, 256, 0, stream>>>(x,  pairs, offs, out, N);
    } else {
        hipMemsetAsync(out, 0, (size_t)N * D * sizeof(float), stream);
        sage_scatter<<<2048, 256, 0, stream>>>(x, esrc, edst, ew, out, E);
    }

    const int nb = (N + 63) / 64;
    sage_linear_norm<<<nb, 256, 0, stream>>>(out, x, Wl, bl, Wr, br, out, N);
}

// Round 6
// 167.325 us; speedup vs baseline: 8.4721x; 1.3914x over previous
//
#include <hip/hip_runtime.h>
#include <hip/hip_fp16.h>

// SAGEConv: agg = segment_sum(x[src]*w, dst); out = agg@W_l + b_l + x@W_r + b_r;
// out /= max(sum|out|, 1e-12) row-wise.  N=100000, E=1600000, D=128.
//
// R6: MFMA-ize the linear stage. fp32 VALU GEMM had a ~42us structural floor
// (hit 106us); fp16-input/fp32-accum mfma_f32_16x16x32_f16 moves the GEMM to
// the matrix pipe. Gather writes fp16 agg; W pre-transposed to fp16 WT[col][k]
// once so all MFMA fragments are contiguous-k ds_read_b128 (m97 pattern).

static constexpr int D = 128;
static constexpr int NB = 1024;     // coarse buckets
static constexpr int CBITS = 7;     // nodes per bucket = 128
static constexpr int CSZ = 1 << CBITS;

typedef _Float16 half8 __attribute__((ext_vector_type(8)));
typedef float f32x4 __attribute__((ext_vector_type(4)));

// ---------------- x -> fp16 staging ----------------
__global__ __launch_bounds__(256) void cvt_x_fp16(
    const float4* __restrict__ x4, __half2* __restrict__ xh2, int n4)
{
    int i = blockIdx.x * blockDim.x + threadIdx.x;
    int stride = gridDim.x * blockDim.x;
    for (; i < n4; i += stride) {
        float4 v = x4[i];
        xh2[2 * i + 0] = __floats2half2_rn(v.x, v.y);
        xh2[2 * i + 1] = __floats2half2_rn(v.z, v.w);
    }
}

// ---------------- W pre-transpose: WT[c][k] fp16, k<128 -> Wl, else Wr ----
__global__ __launch_bounds__(256) void wt_build(
    const float* __restrict__ Wl, const float* __restrict__ Wr,
    __half* __restrict__ wt)
{
    const int idx = blockIdx.x * blockDim.x + threadIdx.x;  // 128 blocks x 256
    if (idx >= 128 * 256) return;
    const int c = idx >> 8;
    const int k = idx & 255;
    const float v = (k < 128) ? Wl[(size_t)k * D + c] : Wr[(size_t)(k - 128) * D + c];
    wt[(size_t)c * 256 + k] = __float2half(v);
}

// ---------------- two-level counting sort ----------------
__global__ __launch_bounds__(256) void coarse_count(
    const int* __restrict__ edst, int* __restrict__ ccnt, int E, int chunk)
{
    __shared__ int hist[NB];
    for (int t = threadIdx.x; t < NB; t += 256) hist[t] = 0;
    __syncthreads();
    const int beg = blockIdx.x * chunk;
    const int end = min(E, beg + chunk);
    for (int e = beg + threadIdx.x; e < end; e += 256)
        atomicAdd(&hist[edst[e] >> CBITS], 1);
    __syncthreads();
    for (int t = threadIdx.x; t < NB; t += 256) {
        const int c = hist[t];
        if (c) atomicAdd(&ccnt[t], c);
    }
}

__global__ __launch_bounds__(NB) void coarse_scan(
    const int* __restrict__ ccnt, int* __restrict__ cbase,
    int* __restrict__ ccur, int* __restrict__ offs, int N, int E)
{
    __shared__ int s[NB];
    const int t = threadIdx.x;
    const int v = ccnt[t];
    s[t] = v;
    __syncthreads();
    for (int off = 1; off < NB; off <<= 1) {
        const int u = (t >= off) ? s[t - off] : 0;
        __syncthreads();
        s[t] += u;
        __syncthreads();
    }
    const int excl = s[t] - v;
    cbase[t] = excl;
    ccur[t]  = excl;
    if (t == NB - 1) { cbase[NB] = s[t]; offs[N] = E; }
}

__global__ __launch_bounds__(256) void coarse_partition(
    const int* __restrict__ esrc, const int* __restrict__ edst,
    const float* __restrict__ ew, int* ccur,
    int2* __restrict__ cpairs, int E, int chunk)
{
    __shared__ int hist[NB];
    for (int t = threadIdx.x; t < NB; t += 256) hist[t] = 0;
    __syncthreads();
    const int beg = blockIdx.x * chunk;
    const int end = min(E, beg + chunk);
    for (int e = beg + threadIdx.x; e < end; e += 256)
        atomicAdd(&hist[edst[e] >> CBITS], 1);
    __syncthreads();
    for (int t = threadIdx.x; t < NB; t += 256) {
        const int c = hist[t];
        hist[t] = c ? atomicAdd(&ccur[t], c) : 0;   // hist becomes global cursor
    }
    __syncthreads();
    for (int e = beg + threadIdx.x; e < end; e += 256) {
        const int d = edst[e];
        const int pos = atomicAdd(&hist[d >> CBITS], 1);
        cpairs[pos] = make_int2(((d & (CSZ - 1)) << 20) | esrc[e],
                                __float_as_int(ew[e]));
    }
}

__global__ __launch_bounds__(256) void fine_sort(
    const int2* __restrict__ cpairs, const int* __restrict__ cbase,
    int* __restrict__ offs, int2* __restrict__ pairs, int N)
{
    __shared__ int hist[CSZ];
    __shared__ int scn[CSZ];
    const int b = blockIdx.x;
    const int t = threadIdx.x;
    const int s0 = cbase[b], s1 = cbase[b + 1];
    if (t < CSZ) hist[t] = 0;
    __syncthreads();
    for (int i = s0 + t; i < s1; i += 256)
        atomicAdd(&hist[(cpairs[i].x >> 20) & (CSZ - 1)], 1);
    __syncthreads();
    if (t < CSZ) scn[t] = hist[t];
    __syncthreads();
    for (int off = 1; off < CSZ; off <<= 1) {
        int u = 0;
        if (t < CSZ && t >= off) u = scn[t - off];
        __syncthreads();
        if (t < CSZ) scn[t] += u;
        __syncthreads();
    }
    if (t < CSZ) {
        const int base = s0 + scn[t] - hist[t];   // exclusive
        const int node = (b << CBITS) + t;
        if (node < N) offs[node] = base;
        hist[t] = base;                            // becomes cursor
    }
    __syncthreads();
    for (int i = s0 + t; i < s1; i += 256) {
        const int2 p = cpairs[i];
        const int pos = atomicAdd(&hist[(p.x >> 20) & (CSZ - 1)], 1);
        pairs[pos] = make_int2(p.x & 0xFFFFF, p.y);
    }
}

// ---------------- gather-aggregate: one wave per node ----------------
// FP16X: x staged fp16, agg written fp16; else fp32 in / fp32 out.
template <bool FP16X>
__global__ __launch_bounds__(256) void sage_gather(
    const void* __restrict__ xrows,
    const int2* __restrict__ pairs,
    const int* __restrict__ offs,
    void* __restrict__ agg,
    int N)
{
    int node = (blockIdx.x * blockDim.x + threadIdx.x) >> 6;
    const int lane = threadIdx.x & 63;
    if (node >= N) return;
    node = __builtin_amdgcn_readfirstlane(node);
    const int beg = offs[node];
    const int end = offs[node + 1];

    const __half2* __restrict__ xh = (const __half2*)xrows;
    const float2*  __restrict__ xf = (const float2*)xrows;

    float ax0 = 0.f, ay0 = 0.f, ax1 = 0.f, ay1 = 0.f;
    int k = beg;
    for (; k + 4 <= end; k += 4) {
        const int2 p0 = pairs[k + 0];
        const int2 p1 = pairs[k + 1];
        const int2 p2 = pairs[k + 2];
        const int2 p3 = pairs[k + 3];
        float2 v0, v1, v2, v3;
        if (FP16X) {
            v0 = __half22float2(xh[(size_t)p0.x * 64 + lane]);
            v1 = __half22float2(xh[(size_t)p1.x * 64 + lane]);
            v2 = __half22float2(xh[(size_t)p2.x * 64 + lane]);
            v3 = __half22float2(xh[(size_t)p3.x * 64 + lane]);
        } else {
            v0 = xf[(size_t)p0.x * 64 + lane];
            v1 = xf[(size_t)p1.x * 64 + lane];
            v2 = xf[(size_t)p2.x * 64 + lane];
            v3 = xf[(size_t)p3.x * 64 + lane];
        }
        const float w0 = __int_as_float(p0.y), w1 = __int_as_float(p1.y);
        const float w2 = __int_as_float(p2.y), w3 = __int_as_float(p3.y);
        ax0 = fmaf(v0.x, w0, ax0); ay0 = fmaf(v0.y, w0, ay0);
        ax1 = fmaf(v1.x, w1, ax1); ay1 = fmaf(v1.y, w1, ay1);
        ax0 = fmaf(v2.x, w2, ax0); ay0 = fmaf(v2.y, w2, ay0);
        ax1 = fmaf(v3.x, w3, ax1); ay1 = fmaf(v3.y, w3, ay1);
    }
    for (; k < end; ++k) {
        const int2 p = pairs[k];
        const float w = __int_as_float(p.y);
        float2 v;
        if (FP16X) v = __half22float2(xh[(size_t)p.x * 64 + lane]);
        else       v = xf[(size_t)p.x * 64 + lane];
        ax0 = fmaf(v.x, w, ax0); ay0 = fmaf(v.y, w, ay0);
    }
    if (FP16X) {
        ((__half2*)agg)[(size_t)node * 64 + lane] =
            __floats2half2_rn(ax0 + ax1, ay0 + ay1);
    } else {
        ((float2*)agg)[(size_t)node * 64 + lane] =
            make_float2(ax0 + ax1, ay0 + ay1);
    }
}

// ---------------- fallback atomic scatter (ws too small) ----------------
__global__ __launch_bounds__(256) void sage_scatter(
    const float* __restrict__ x,
    const int* __restrict__ esrc,
    const int* __restrict__ edst,
    const float* __restrict__ ew,
    float* agg, int E)
{
    const int lane = threadIdx.x & 63;
    const int warp = (blockIdx.x * blockDim.x + threadIdx.x) >> 6;
    const int nwarps = (gridDim.x * blockDim.x) >> 6;
    const float2* __restrict__ x2 = reinterpret_cast<const float2*>(x);
    for (int e = warp; e < E; e += nwarps) {
        const int s = esrc[e];
        const int d = edst[e];
        const float w = ew[e];
        const float2 xv = x2[s * 64 + lane];
        atomicAdd(&agg[d * D + lane * 2 + 0], xv.x * w);
        atomicAdd(&agg[d * D + lane * 2 + 1], xv.y * w);
    }
}

// ------------- MFMA fused linear(l)+linear(r)+bias+L1-normalize -------------
// block: 256 thr = 4 waves, 64 nodes x 128 cols. Wave w owns rows [w*16,+16)
// (complete rows -> intra-wave L1 norm). K=256 as 2 chunks (aggh then xh).
// A_s[64][136], W_s[128][136] fp16 (+16B row pad -> 2-way-free bank pattern).
__global__ __launch_bounds__(256) void sage_linear_norm_mfma(
    const __half* __restrict__ aggh,   // [N][128]
    const __half* __restrict__ xh,     // [N][128]
    const __half* __restrict__ wt,     // [128 cols][256 k]
    const float* __restrict__ bl,
    const float* __restrict__ br,
    float* __restrict__ out,
    int N)
{
    __shared__ __half a_s[64][136];
    __shared__ __half w_s[128][136];
    const int tid = threadIdx.x;
    const int bn = blockIdx.x * 64;
    const int wv = tid >> 6;     // wave -> row group
    const int l  = tid & 63;
    const int lr = l & 15;       // fragment row/col
    const int lq = l >> 4;       // quarter -> k-subrange / C row group

    f32x4 acc[8];
#pragma unroll
    for (int t = 0; t < 8; ++t) acc[t] = f32x4{0.f, 0.f, 0.f, 0.f};

    const int ar  = tid >> 2;          // A staging: row 0..63
    const int as  = (tid & 3) * 32;    // A staging: half offset (64B)
    const int wr  = tid >> 1;          // W staging: col-row 0..127
    const int wsg = (tid & 1) * 64;    // W staging: half offset (128B)

#pragma unroll
    for (int c = 0; c < 2; ++c) {
        const __half* __restrict__ A = c ? xh : aggh;
        __syncthreads();   // previous chunk consumed
        {
            const int gn = bn + ar;
            half8 v0 = {}, v1 = {}, v2 = {}, v3 = {};
            if (gn < N) {
                const half8* src = reinterpret_cast<const half8*>(&A[(size_t)gn * D + as]);
                v0 = src[0]; v1 = src[1]; v2 = src[2]; v3 = src[3];
            }
            half8* dst = reinterpret_cast<half8*>(&a_s[ar][as]);
            dst[0] = v0; dst[1] = v1; dst[2] = v2; dst[3] = v3;
        }
        {
            const half8* src = reinterpret_cast<const half8*>(&wt[(size_t)wr * 256 + c * 128 + wsg]);
            half8* dst = reinterpret_cast<half8*>(&w_s[wr][wsg]);
#pragma unroll
            for (int j = 0; j < 8; ++j) dst[j] = src[j];
        }
        __syncthreads();

#pragma unroll
        for (int ks = 0; ks < 4; ++ks) {
            const int k0 = ks * 32 + lq * 8;
            const half8 af = *reinterpret_cast<const half8*>(&a_s[wv * 16 + lr][k0]);
#pragma unroll
            for (int t = 0; t < 8; ++t) {
                const half8 bf = *reinterpret_cast<const half8*>(&w_s[t * 16 + lr][k0]);
                acc[t] = __builtin_amdgcn_mfma_f32_16x16x32_f16(af, bf, acc[t], 0, 0, 0);
            }
        }
    }

    // epilogue: bias + |.| row-sum (shfl over the 16 col-lanes) + normalize
    float bias[8];
#pragma unroll
    for (int t = 0; t < 8; ++t) {
        const int cidx = t * 16 + lr;
        bias[t] = bl[cidx] + br[cidx];
    }
    float v[8][4];
    float s0 = 0.f, s1 = 0.f, s2 = 0.f, s3 = 0.f;
#pragma unroll
    for (int t = 0; t < 8; ++t) {
        v[t][0] = acc[t][0] + bias[t];
        v[t][1] = acc[t][1] + bias[t];
        v[t][2] = acc[t][2] + bias[t];
        v[t][3] = acc[t][3] + bias[t];
        s0 += fabsf(v[t][0]); s1 += fabsf(v[t][1]);
        s2 += fabsf(v[t][2]); s3 += fabsf(v[t][3]);
    }
#pragma unroll
    for (int m = 1; m < 16; m <<= 1) {
        s0 += __shfl_xor(s0, m, 64);
        s1 += __shfl_xor(s1, m, 64);
        s2 += __shfl_xor(s2, m, 64);
        s3 += __shfl_xor(s3, m, 64);
    }
    const float r0 = 1.0f / fmaxf(s0, 1e-12f);
    const float r1 = 1.0f / fmaxf(s1, 1e-12f);
    const float r2 = 1.0f / fmaxf(s2, 1e-12f);
    const float r3 = 1.0f / fmaxf(s3, 1e-12f);

    const int nd0 = bn + wv * 16 + lq * 4;
#pragma unroll
    for (int r = 0; r < 4; ++r) {
        const int nd = nd0 + r;
        if (nd < N) {
            const float ri = (r == 0) ? r0 : (r == 1) ? r1 : (r == 2) ? r2 : r3;
#pragma unroll
            for (int t = 0; t < 8; ++t)
                out[(size_t)nd * D + t * 16 + lr] = v[t][r] * ri;
        }
    }
}

// ------------- fp32 fallback linear (tier B/C) -------------
__global__ __launch_bounds__(256) void sage_linear_norm(
    const float* agg, const float* __restrict__ x,
    const float* __restrict__ Wl, const float* __restrict__ bl,
    const float* __restrict__ Wr, const float* __restrict__ br,
    float* out, int N)
{
    __shared__ float a_s[64][68];
    __shared__ float w_s[64][132];
    const int tid = threadIdx.x;
    const int jg = tid & 31;
    const int ng = tid >> 5;
    const int bn = blockIdx.x * 64;

    float acc[8][4];
#pragma unroll
    for (int i = 0; i < 8; ++i) {
        acc[i][0] = 0.f; acc[i][1] = 0.f; acc[i][2] = 0.f; acc[i][3] = 0.f;
    }
    const int sn  = tid >> 2;
    const int skb = (tid & 3) << 4;
    const int wr  = tid >> 5;
    const int wc  = (tid & 31) << 2;

    for (int c = 0; c < 4; ++c) {
        const float* A = (c < 2) ? agg : x;
        const float* __restrict__ W = (c < 2) ? Wl : Wr;
        const int kb = (c & 1) << 6;
        __syncthreads();
        const int gn = bn + sn;
#pragma unroll
        for (int it = 0; it < 4; ++it) {
            float4 vv = make_float4(0.f, 0.f, 0.f, 0.f);
            if (gn < N)
                vv = *reinterpret_cast<const float4*>(&A[(size_t)gn * D + kb + skb + it * 4]);
            *reinterpret_cast<float4*>(&a_s[sn][skb + it * 4]) = vv;
        }
#pragma unroll
        for (int it = 0; it < 8; ++it) {
            const int row = it * 8 + wr;
            const float4 vv = *reinterpret_cast<const float4*>(&W[(size_t)(kb + row) * D + wc]);
            *reinterpret_cast<float4*>(&w_s[row][wc]) = vv;
        }
        __syncthreads();
#pragma unroll 4
        for (int kk = 0; kk < 64; kk += 4) {
            const float4 w0 = *reinterpret_cast<const float4*>(&w_s[kk + 0][jg << 2]);
            const float4 w1 = *reinterpret_cast<const float4*>(&w_s[kk + 1][jg << 2]);
            const float4 w2 = *reinterpret_cast<const float4*>(&w_s[kk + 2][jg << 2]);
            const float4 w3 = *reinterpret_cast<const float4*>(&w_s[kk + 3][jg << 2]);
#pragma unroll
            for (int i = 0; i < 8; ++i) {
                const float4 av = *reinterpret_cast<const float4*>(&a_s[(ng << 3) + i][kk]);
                acc[i][0] = fmaf(av.w, w3.x, fmaf(av.z, w2.x, fmaf(av.y, w1.x, fmaf(av.x, w0.x, acc[i][0]))));
                acc[i][1] = fmaf(av.w, w3.y, fmaf(av.z, w2.y, fmaf(av.y, w1.y, fmaf(av.x, w0.y, acc[i][1]))));
                acc[i][2] = fmaf(av.w, w3.z, fmaf(av.z, w2.z, fmaf(av.y, w1.z, fmaf(av.x, w0.z, acc[i][2]))));
                acc[i][3] = fmaf(av.w, w3.w, fmaf(av.z, w2.w, fmaf(av.y, w1.w, fmaf(av.x, w0.w, acc[i][3]))));
            }
        }
    }
    const float4 bl4 = *reinterpret_cast<const float4*>(&bl[jg << 2]);
    const float4 br4 = *reinterpret_cast<const float4*>(&br[jg << 2]);
    const float bx = bl4.x + br4.x, by = bl4.y + br4.y,
                bz = bl4.z + br4.z, bw = bl4.w + br4.w;
#pragma unroll
    for (int i = 0; i < 8; ++i) {
        const float v0 = acc[i][0] + bx;
        const float v1 = acc[i][1] + by;
        const float v2 = acc[i][2] + bz;
        const float v3 = acc[i][3] + bw;
        float s = fabsf(v0) + fabsf(v1) + fabsf(v2) + fabsf(v3);
#pragma unroll
        for (int m = 1; m < 32; m <<= 1) s += __shfl_xor(s, m, 64);
        s = fmaxf(s, 1e-12f);
        const float r = 1.0f / s;
        const int n = bn + (ng << 3) + i;
        if (n < N) {
            const float4 o = make_float4(v0 * r, v1 * r, v2 * r, v3 * r);
            *reinterpret_cast<float4*>(&out[(size_t)n * D + (jg << 2)]) = o;
        }
    }
}

extern "C" void kernel_launch(void* const* d_in, const int* in_sizes, int n_in,
                              void* d_out, int out_size, void* d_ws, size_t ws_size,
                              hipStream_t stream) {
    const float* x    = (const float*)d_in[0];
    const int*   esrc = (const int*)  d_in[1];
    const int*   edst = (const int*)  d_in[2];
    const float* ew   = (const float*)d_in[3];
    const float* Wl   = (const float*)d_in[4];
    const float* bl   = (const float*)d_in[5];
    const float* Wr   = (const float*)d_in[6];
    const float* br   = (const float*)d_in[7];
    float* out = (float*)d_out;

    const int N = in_sizes[0] / D;
    const int E = in_sizes[1];

    // ws: ccnt|cbase|ccur|offs | cpairs[E] | pairs[E] | xh | aggh | wt
    auto align256 = [](size_t v) { return (v + 255) & ~size_t(255); };
    size_t off_ccnt   = 0;
    size_t off_cbase  = align256(off_ccnt   + (size_t)NB * 4);
    size_t off_ccur   = align256(off_cbase  + (size_t)(NB + 1) * 4);
    size_t off_offs   = align256(off_ccur   + (size_t)NB * 4);
    size_t off_cpairs = align256(off_offs   + (size_t)(N + 1) * 4);
    size_t off_pairs  = align256(off_cpairs + (size_t)E * 8);
    size_t off_xh     = align256(off_pairs  + (size_t)E * 8);
    size_t off_aggh   = align256(off_xh     + (size_t)N * D * 2);
    size_t off_wt     = align256(off_aggh   + (size_t)N * D * 2);
    size_t need_b     = off_xh;                        // sorted fp32 path
    size_t need_a     = off_wt + (size_t)256 * D * 2;  // full fp16 MFMA path

    const bool fits_meta = (N <= (1 << 20)) && ((N + CSZ - 1) >> CBITS) <= NB;

    if (ws_size >= need_b && fits_meta) {
        char* ws = (char*)d_ws;
        int*  ccnt   = (int*) (ws + off_ccnt);
        int*  cbase  = (int*) (ws + off_cbase);
        int*  ccur   = (int*) (ws + off_ccur);
        int*  offs   = (int*) (ws + off_offs);
        int2* cpairs = (int2*)(ws + off_cpairs);
        int2* pairs  = (int2*)(ws + off_pairs);
        __half2* xh  = (__half2*)(ws + off_xh);
        __half*  agh = (__half*)(ws + off_aggh);
        __half*  wt  = (__half*)(ws + off_wt);

        const bool mfma = (ws_size >= need_a);
        const int chunk = (E + 255) / 256;
        const int nbu = (N + CSZ - 1) >> CBITS;

        hipMemsetAsync(ccnt, 0, (size_t)NB * 4, stream);
        if (mfma) {
            cvt_x_fp16<<<4096, 256, 0, stream>>>((const float4*)x, xh, N * (D / 4));
            wt_build<<<128, 256, 0, stream>>>(Wl, Wr, wt);
        }
        coarse_count<<<256, 256, 0, stream>>>(edst, ccnt, E, chunk);
        coarse_scan<<<1, NB, 0, stream>>>(ccnt, cbase, ccur, offs, N, E);
        coarse_partition<<<256, 256, 0, stream>>>(esrc, edst, ew, ccur, cpairs, E, chunk);
        fine_sort<<<nbu, 256, 0, stream>>>(cpairs, cbase, offs, pairs, N);

        const int gb = (N * 64 + 255) / 256;   // one wave per node
        const int nb = (N + 63) / 64;
        if (mfma) {
            sage_gather<true ><<<gb, 256, 0, stream>>>(xh, pairs, offs, agh, N);
            sage_linear_norm_mfma<<<nb, 256, 0, stream>>>(agh, (const __half*)xh, wt,
                                                          bl, br, out, N);
        } else {
            sage_gather<false><<<gb, 256, 0, stream>>>(x, pairs, offs, out, N);
            sage_linear_norm<<<nb, 256, 0, stream>>>(out, x, Wl, bl, Wr, br, out, N);
        }
    } else {
        hipMemsetAsync(out, 0, (size_t)N * D * sizeof(float), stream);
        sage_scatter<<<2048, 256, 0, stream>>>(x, esrc, edst, ew, out, E);
        const int nb = (N + 63) / 64;
        sage_linear_norm<<<nb, 256, 0, stream>>>(out, x, Wl, bl, Wr, br, out, N);
    }
}